// Round 1
// baseline (152.840 us; speedup 1.0000x reference)
//
#include <hip/hip_runtime.h>
#include <math.h>

#define BB 8
#define NN 2048
#define FF 128
#define NP1 (NN + 1)
#define LALPHA 0.2f

#define WT_STRIDE 132   // 128 + 4 pad: conflict-light transposed W writes, float4-aligned reads
#define XT_STRIDE 18    // 16 + 2 pad, float2-aligned

// ---------------- K1: h = x @ W^T, si = h.a1, sj = h.a2 ----------------
// grid = B*N/16 blocks, 256 threads. Each thread: 2 rows x 4 features.
__global__ __launch_bounds__(256, 2)
void k1_h(const float* __restrict__ x, const float* __restrict__ W,
          const float* __restrict__ a, float* __restrict__ h,
          float* __restrict__ si, float* __restrict__ sj)
{
    __shared__ float Wt[FF * WT_STRIDE];   // Wt[f*WT_STRIDE + o] = W[o][f]
    __shared__ float xsT[FF * XT_STRIDE];  // xsT[f*XT_STRIDE + r] = x[row0+r][f]
    const int t = threadIdx.x;
    const int row0 = blockIdx.x * 16;

    for (int kk = t; kk < FF * FF; kk += 256) {
        int o = kk >> 7, f = kk & (FF - 1);
        Wt[f * WT_STRIDE + o] = W[kk];
    }
    for (int kk = t; kk < 16 * FF; kk += 256) {
        int r = kk >> 7, f = kk & (FF - 1);
        xsT[f * XT_STRIDE + r] = x[(row0 + r) * FF + f];
    }
    __syncthreads();

    const int oq = (t & 31) << 2;  // feature quad base
    const int rp = t >> 5;         // row pair 0..7 -> rows 2rp, 2rp+1
    float a00 = 0.f, a01 = 0.f, a02 = 0.f, a03 = 0.f;
    float a10 = 0.f, a11 = 0.f, a12 = 0.f, a13 = 0.f;
#pragma unroll 8
    for (int f = 0; f < FF; ++f) {
        float2 xv = *(const float2*)&xsT[f * XT_STRIDE + (rp << 1)];
        float4 wv = *(const float4*)&Wt[f * WT_STRIDE + oq];
        a00 += xv.x * wv.x; a01 += xv.x * wv.y; a02 += xv.x * wv.z; a03 += xv.x * wv.w;
        a10 += xv.y * wv.x; a11 += xv.y * wv.y; a12 += xv.y * wv.z; a13 += xv.y * wv.w;
    }
    const int r0 = row0 + (rp << 1), r1 = r0 + 1;
    *(float4*)&h[r0 * FF + oq] = make_float4(a00, a01, a02, a03);
    *(float4*)&h[r1 * FF + oq] = make_float4(a10, a11, a12, a13);

    const float4 a1v = *(const float4*)&a[oq];
    const float4 a2v = *(const float4*)&a[FF + oq];
    float s10 = a00 * a1v.x + a01 * a1v.y + a02 * a1v.z + a03 * a1v.w;
    float s11 = a10 * a1v.x + a11 * a1v.y + a12 * a1v.z + a13 * a1v.w;
    float s20 = a00 * a2v.x + a01 * a2v.y + a02 * a2v.z + a03 * a2v.w;
    float s21 = a10 * a2v.x + a11 * a2v.y + a12 * a2v.z + a13 * a2v.w;
#pragma unroll
    for (int off = 16; off >= 1; off >>= 1) {
        s10 += __shfl_down(s10, off, 32);
        s11 += __shfl_down(s11, off, 32);
        s20 += __shfl_down(s20, off, 32);
        s21 += __shfl_down(s21, off, 32);
    }
    if ((t & 31) == 0) {
        si[r0] = s10; si[r1] = s11;
        sj[r0] = s20; sj[r1] = s21;
    }
}

// ---------------- K2: per-batch bitonic sort of sj (ascending) ----------------
// grid = B blocks, 1024 threads, 2048 elements in LDS.
__global__ __launch_bounds__(1024)
void k2_sort(const float* __restrict__ sj, float* __restrict__ keys, int* __restrict__ sidx)
{
    __shared__ float k[NN];
    __shared__ int ix[NN];
    const int b = blockIdx.x, t = threadIdx.x;
    k[t] = sj[b * NN + t];              ix[t] = t;
    k[t + 1024] = sj[b * NN + t + 1024]; ix[t + 1024] = t + 1024;

    for (int kk = 2; kk <= NN; kk <<= 1) {
        for (int j = kk >> 1; j > 0; j >>= 1) {
            __syncthreads();
            int i = ((t & ~(j - 1)) << 1) | (t & (j - 1));
            int p = i | j;
            bool up = ((i & kk) == 0);
            float ki = k[i], kp = k[p];
            if ((ki > kp) == up) {
                k[i] = kp; k[p] = ki;
                int tmp = ix[i]; ix[i] = ix[p]; ix[p] = tmp;
            }
        }
    }
    __syncthreads();
    keys[b * NN + t] = k[t];               sidx[b * NN + t] = ix[t];
    keys[b * NN + t + 1024] = k[t + 1024]; sidx[b * NN + t + 1024] = ix[t + 1024];
}

// ---------------- K3: prefix/suffix scans over sorted order ----------------
// grid = 2*B blocks (b, dir), 1024 threads = 8 chunks x 128 features.
// dir==0: P2[p][o] = sum_{m<p} e^{0.2*key[m]} * h[idx[m]][o]   (exclusive prefix)
//         T2[p]    = scalar version
// dir==1: S1[p][o] = sum_{m>=p} e^{key[m]} * h[idx[m]][o]      (inclusive suffix)
//         T1[p]    = scalar version
__global__ __launch_bounds__(1024)
void k3_scan(const float* __restrict__ h, const float* __restrict__ keys,
             const int* __restrict__ sidx,
             float* __restrict__ S1, float* __restrict__ P2,
             float* __restrict__ T1, float* __restrict__ T2)
{
    const int bid = blockIdx.x;
    const int b = bid >> 1, dir = bid & 1;
    const int t = threadIdx.x;
    const int g = t >> 7, o = t & 127;
    __shared__ float csum[8][128];
    __shared__ float scs[8];
    __shared__ float lk[NN];
    __shared__ int li[NN];

    for (int i = t; i < NN; i += 1024) {
        lk[i] = keys[b * NN + i];
        li[i] = sidx[b * NN + i];
    }
    __syncthreads();

    const int m0 = g << 8;  // chunk of 256
    // phase 1: chunk sums
    float cs = 0.f, ss = 0.f;
#pragma unroll 4
    for (int m = m0; m < m0 + 256; ++m) {
        float w = expf(dir ? lk[m] : LALPHA * lk[m]);
        cs += w * h[(b * NN + li[m]) * FF + o];
        ss += w;
    }
    csum[g][o] = cs;
    if (o == 0) scs[g] = ss;
    __syncthreads();

    // phase 2: chunk bases
    float base = 0.f, sbase = 0.f;
    if (dir == 0) {
        for (int g2 = 0; g2 < g; ++g2) { base += csum[g2][o]; sbase += scs[g2]; }
    } else {
        for (int g2 = g + 1; g2 < 8; ++g2) { base += csum[g2][o]; sbase += scs[g2]; }
    }

    // phase 3: rescan, write rows
    if (dir == 0) {
        float acc = base, sacc = sbase;
#pragma unroll 4
        for (int m = m0; m < m0 + 256; ++m) {
            P2[(b * NP1 + m) * FF + o] = acc;
            if (o == 0) T2[b * NP1 + m] = sacc;
            float w = expf(LALPHA * lk[m]);
            acc += w * h[(b * NN + li[m]) * FF + o];
            sacc += w;
        }
        if (g == 7) {
            P2[(b * NP1 + NN) * FF + o] = acc;
            if (o == 0) T2[b * NP1 + NN] = sacc;
        }
    } else {
        float acc = base, sacc = sbase;
        if (g == 7) {
            S1[(b * NP1 + NN) * FF + o] = 0.f;
            if (o == 0) T1[b * NP1 + NN] = 0.f;
        }
#pragma unroll 4
        for (int m = m0 + 255; m >= m0; --m) {
            float w = expf(lk[m]);
            acc += w * h[(b * NN + li[m]) * FF + o];
            sacc += w;
            S1[(b * NP1 + m) * FF + o] = acc;
            if (o == 0) T1[b * NP1 + m] = sacc;
        }
    }
}

// ---------------- K4: per-row binary search + blend ----------------
// grid = B*N blocks, 128 threads.
__global__ __launch_bounds__(128)
void k4_out(const float* __restrict__ si, const float* __restrict__ keys,
            const float* __restrict__ S1, const float* __restrict__ P2,
            const float* __restrict__ T1, const float* __restrict__ T2,
            float* __restrict__ out)
{
    const int bi = blockIdx.x;
    const int b = bi >> 11, i = bi & (NN - 1);
    const int o = threadIdx.x;
    const float siv = si[b * NN + i];
    const float thr = -siv;
    const float* kb = keys + b * NN;
    int lo = 0, hi = NN;
    while (lo < hi) {             // lower_bound: first m with key[m] >= -si
        int mid = (lo + hi) >> 1;
        if (kb[mid] < thr) lo = mid + 1; else hi = mid;
    }
    const int p = lo;
    const float e1 = expf(siv), e2 = expf(LALPHA * siv);
    const float den = e1 * T1[b * NP1 + p] + e2 * T2[b * NP1 + p];
    const float num = e1 * S1[(b * NP1 + p) * FF + o] + e2 * P2[(b * NP1 + p) * FF + o];
    out[(b * NN + i) * FF + o] = num / den;
}

extern "C" void kernel_launch(void* const* d_in, const int* in_sizes, int n_in,
                              void* d_out, int out_size, void* d_ws, size_t ws_size,
                              hipStream_t stream)
{
    const float* x = (const float*)d_in[0];
    const float* W = (const float*)d_in[1];
    const float* a = (const float*)d_in[2];
    float* out = (float*)d_out;

    float* ws = (float*)d_ws;
    float* h    = ws;                        // B*N*F
    float* S1   = h + BB * NN * FF;          // B*NP1*F
    float* P2   = S1 + BB * NP1 * FF;        // B*NP1*F
    float* si   = P2 + BB * NP1 * FF;        // B*N
    float* sj   = si + BB * NN;              // B*N
    float* keys = sj + BB * NN;              // B*N
    int*   sidx = (int*)(keys + BB * NN);    // B*N
    float* T1   = (float*)(sidx + BB * NN);  // B*NP1
    float* T2   = T1 + BB * NP1;             // B*NP1

    hipLaunchKernelGGL(k1_h, dim3(BB * NN / 16), dim3(256), 0, stream, x, W, a, h, si, sj);
    hipLaunchKernelGGL(k2_sort, dim3(BB), dim3(1024), 0, stream, sj, keys, sidx);
    hipLaunchKernelGGL(k3_scan, dim3(2 * BB), dim3(1024), 0, stream, h, keys, sidx, S1, P2, T1, T2);
    hipLaunchKernelGGL(k4_out, dim3(BB * NN), dim3(128), 0, stream, si, keys, S1, P2, T1, T2, out);
}

// Round 2
// 87.884 us; speedup vs baseline: 1.7391x; 1.7391x over previous
//
#include <hip/hip_runtime.h>
#include <math.h>

#define BB 8
#define NN 2048
#define FF 128
#define NP1 (NN + 1)
#define LALPHA 0.2f

#define CH 64
#define NCH (NN / CH)   // 32

#define WT_STRIDE 132   // 128 + 4 pad
#define XT_STRIDE 18    // 16 + 2 pad

// ---------------- K1: h = x @ W^T, si = h.a1, sj = h.a2 ----------------
__global__ __launch_bounds__(256, 2)
void k1_h(const float* __restrict__ x, const float* __restrict__ W,
          const float* __restrict__ a, float* __restrict__ h,
          float* __restrict__ si, float* __restrict__ sj)
{
    __shared__ float Wt[FF * WT_STRIDE];   // Wt[f*WT_STRIDE + o] = W[o][f]
    __shared__ float xsT[FF * XT_STRIDE];  // xsT[f*XT_STRIDE + r] = x[row0+r][f]
    const int t = threadIdx.x;
    const int row0 = blockIdx.x * 16;

    for (int kk = t; kk < FF * FF; kk += 256) {
        int o = kk >> 7, f = kk & (FF - 1);
        Wt[f * WT_STRIDE + o] = W[kk];
    }
    for (int kk = t; kk < 16 * FF; kk += 256) {
        int r = kk >> 7, f = kk & (FF - 1);
        xsT[f * XT_STRIDE + r] = x[(row0 + r) * FF + f];
    }
    __syncthreads();

    const int oq = (t & 31) << 2;
    const int rp = t >> 5;
    float a00 = 0.f, a01 = 0.f, a02 = 0.f, a03 = 0.f;
    float a10 = 0.f, a11 = 0.f, a12 = 0.f, a13 = 0.f;
#pragma unroll 8
    for (int f = 0; f < FF; ++f) {
        float2 xv = *(const float2*)&xsT[f * XT_STRIDE + (rp << 1)];
        float4 wv = *(const float4*)&Wt[f * WT_STRIDE + oq];
        a00 += xv.x * wv.x; a01 += xv.x * wv.y; a02 += xv.x * wv.z; a03 += xv.x * wv.w;
        a10 += xv.y * wv.x; a11 += xv.y * wv.y; a12 += xv.y * wv.z; a13 += xv.y * wv.w;
    }
    const int r0 = row0 + (rp << 1), r1 = r0 + 1;
    *(float4*)&h[r0 * FF + oq] = make_float4(a00, a01, a02, a03);
    *(float4*)&h[r1 * FF + oq] = make_float4(a10, a11, a12, a13);

    const float4 a1v = *(const float4*)&a[oq];
    const float4 a2v = *(const float4*)&a[FF + oq];
    float s10 = a00 * a1v.x + a01 * a1v.y + a02 * a1v.z + a03 * a1v.w;
    float s11 = a10 * a1v.x + a11 * a1v.y + a12 * a1v.z + a13 * a1v.w;
    float s20 = a00 * a2v.x + a01 * a2v.y + a02 * a2v.z + a03 * a2v.w;
    float s21 = a10 * a2v.x + a11 * a2v.y + a12 * a2v.z + a13 * a2v.w;
#pragma unroll
    for (int off = 16; off >= 1; off >>= 1) {
        s10 += __shfl_down(s10, off, 32);
        s11 += __shfl_down(s11, off, 32);
        s20 += __shfl_down(s20, off, 32);
        s21 += __shfl_down(s21, off, 32);
    }
    if ((t & 31) == 0) {
        si[r0] = s10; si[r1] = s11;
        sj[r0] = s20; sj[r1] = s21;
    }
}

// ---------------- K2: per-batch bitonic sort of sj (ascending) ----------------
__global__ __launch_bounds__(1024)
void k2_sort(const float* __restrict__ sj, float* __restrict__ keys, int* __restrict__ sidx)
{
    __shared__ float k[NN];
    __shared__ int ix[NN];
    const int b = blockIdx.x, t = threadIdx.x;
    k[t] = sj[b * NN + t];              ix[t] = t;
    k[t + 1024] = sj[b * NN + t + 1024]; ix[t + 1024] = t + 1024;

    for (int kk = 2; kk <= NN; kk <<= 1) {
        for (int j = kk >> 1; j > 0; j >>= 1) {
            __syncthreads();
            int i = ((t & ~(j - 1)) << 1) | (t & (j - 1));
            int p = i | j;
            bool up = ((i & kk) == 0);
            float ki = k[i], kp = k[p];
            if ((ki > kp) == up) {
                k[i] = kp; k[p] = ki;
                int tmp = ix[i]; ix[i] = ix[p]; ix[p] = tmp;
            }
        }
    }
    __syncthreads();
    keys[b * NN + t] = k[t];               sidx[b * NN + t] = ix[t];
    keys[b * NN + t + 1024] = k[t + 1024]; sidx[b * NN + t + 1024] = ix[t + 1024];
}

// ---------------- K3a: per-chunk weighted sums ----------------
// grid = B*2*NCH blocks (bid = (b*2+dir)*NCH + c), 128 threads (one per feature).
// dir==0: weight e^{0.2*key}; dir==1: weight e^{key}.
__global__ __launch_bounds__(128)
void k3a_csum(const float* __restrict__ h, const float* __restrict__ keys,
              const int* __restrict__ sidx,
              float* __restrict__ csum, float* __restrict__ ssum)
{
    const int bid = blockIdx.x;
    const int c = bid & (NCH - 1);
    const int bd = bid / NCH;
    const int dir = bd & 1;
    const int b = bd >> 1;
    const int o = threadIdx.x;
    const int m0 = c * CH;

    __shared__ float lw[CH];
    __shared__ int li[CH];
    if (o < CH) {
        float kv = keys[b * NN + m0 + o];
        lw[o] = expf(dir ? kv : LALPHA * kv);
        li[o] = sidx[b * NN + m0 + o];
    }
    __syncthreads();

    float acc = 0.f, s = 0.f;
#pragma unroll 4
    for (int m = 0; m < CH; ++m) {
        float w = lw[m];
        acc += w * h[(b * NN + li[m]) * FF + o];
        s += w;
    }
    csum[bid * FF + o] = acc;
    if (o == 0) ssum[bid] = s;
}

// ---------------- K3b: chunk base + rescan, write prefix/suffix rows ----------------
__global__ __launch_bounds__(128)
void k3b_write(const float* __restrict__ h, const float* __restrict__ keys,
               const int* __restrict__ sidx,
               const float* __restrict__ csum, const float* __restrict__ ssum,
               float* __restrict__ S1, float* __restrict__ P2,
               float* __restrict__ T1, float* __restrict__ T2)
{
    const int bid = blockIdx.x;
    const int c = bid & (NCH - 1);
    const int bd = bid / NCH;
    const int dir = bd & 1;
    const int b = bd >> 1;
    const int o = threadIdx.x;
    const int m0 = c * CH;

    __shared__ float lw[CH];
    __shared__ int li[CH];
    if (o < CH) {
        float kv = keys[b * NN + m0 + o];
        lw[o] = expf(dir ? kv : LALPHA * kv);
        li[o] = sidx[b * NN + m0 + o];
    }
    __syncthreads();

    const float* cb = csum + (size_t)(bd * NCH) * FF;
    const float* sb_ = ssum + bd * NCH;
    float base = 0.f, sbase = 0.f;
    if (dir == 0) {
        for (int c2 = 0; c2 < c; ++c2) { base += cb[c2 * FF + o]; sbase += sb_[c2]; }
    } else {
        for (int c2 = c + 1; c2 < NCH; ++c2) { base += cb[c2 * FF + o]; sbase += sb_[c2]; }
    }

    if (dir == 0) {
        // exclusive prefix with weight e^{0.2 key}
        float acc = base, sacc = sbase;
#pragma unroll 4
        for (int m = 0; m < CH; ++m) {
            const int gm = m0 + m;
            P2[(size_t)(b * NP1 + gm) * FF + o] = acc;
            if (o == 0) T2[b * NP1 + gm] = sacc;
            float w = lw[m];
            acc += w * h[(b * NN + li[m]) * FF + o];
            sacc += w;
        }
        if (c == NCH - 1) {
            P2[(size_t)(b * NP1 + NN) * FF + o] = acc;
            if (o == 0) T2[b * NP1 + NN] = sacc;
        }
    } else {
        // inclusive suffix with weight e^{key}
        float acc = base, sacc = sbase;
        if (c == NCH - 1) {
            S1[(size_t)(b * NP1 + NN) * FF + o] = 0.f;
            if (o == 0) T1[b * NP1 + NN] = 0.f;
        }
#pragma unroll 4
        for (int m = CH - 1; m >= 0; --m) {
            float w = lw[m];
            acc += w * h[(b * NN + li[m]) * FF + o];
            sacc += w;
            S1[(size_t)(b * NP1 + m0 + m) * FF + o] = acc;
            if (o == 0) T1[b * NP1 + m0 + m] = sacc;
        }
    }
}

// ---------------- K4: per-row binary search + blend ----------------
__global__ __launch_bounds__(128)
void k4_out(const float* __restrict__ si, const float* __restrict__ keys,
            const float* __restrict__ S1, const float* __restrict__ P2,
            const float* __restrict__ T1, const float* __restrict__ T2,
            float* __restrict__ out)
{
    const int bi = blockIdx.x;
    const int b = bi >> 11, i = bi & (NN - 1);
    const int o = threadIdx.x;
    const float siv = si[b * NN + i];
    const float thr = -siv;
    const float* kb = keys + b * NN;
    int lo = 0, hi = NN;
    while (lo < hi) {
        int mid = (lo + hi) >> 1;
        if (kb[mid] < thr) lo = mid + 1; else hi = mid;
    }
    const int p = lo;
    const float e1 = expf(siv), e2 = expf(LALPHA * siv);
    const float den = e1 * T1[b * NP1 + p] + e2 * T2[b * NP1 + p];
    const float num = e1 * S1[(size_t)(b * NP1 + p) * FF + o] + e2 * P2[(size_t)(b * NP1 + p) * FF + o];
    out[(size_t)(b * NN + i) * FF + o] = num / den;
}

extern "C" void kernel_launch(void* const* d_in, const int* in_sizes, int n_in,
                              void* d_out, int out_size, void* d_ws, size_t ws_size,
                              hipStream_t stream)
{
    const float* x = (const float*)d_in[0];
    const float* W = (const float*)d_in[1];
    const float* a = (const float*)d_in[2];
    float* out = (float*)d_out;

    float* ws = (float*)d_ws;
    float* h    = ws;                          // B*N*F
    float* S1   = h + BB * NN * FF;            // B*NP1*F
    float* P2   = S1 + BB * NP1 * FF;          // B*NP1*F
    float* si   = P2 + BB * NP1 * FF;          // B*N
    float* sj   = si + BB * NN;                // B*N
    float* keys = sj + BB * NN;                // B*N
    int*   sidx = (int*)(keys + BB * NN);      // B*N
    float* T1   = (float*)(sidx + BB * NN);    // B*NP1
    float* T2   = T1 + BB * NP1;               // B*NP1
    float* csum = T2 + BB * NP1;               // B*2*NCH*F = 65536
    float* ssum = csum + BB * 2 * NCH * FF;    // B*2*NCH = 512

    hipLaunchKernelGGL(k1_h, dim3(BB * NN / 16), dim3(256), 0, stream, x, W, a, h, si, sj);
    hipLaunchKernelGGL(k2_sort, dim3(BB), dim3(1024), 0, stream, sj, keys, sidx);
    hipLaunchKernelGGL(k3a_csum, dim3(BB * 2 * NCH), dim3(128), 0, stream, h, keys, sidx, csum, ssum);
    hipLaunchKernelGGL(k3b_write, dim3(BB * 2 * NCH), dim3(128), 0, stream, h, keys, sidx, csum, ssum, S1, P2, T1, T2);
    hipLaunchKernelGGL(k4_out, dim3(BB * NN), dim3(128), 0, stream, si, keys, S1, P2, T1, T2, out);
}